// Round 1
// baseline (1878.097 us; speedup 1.0000x reference)
//
#include <hip/hip_runtime.h>

// GNN: 2-layer hetero SAGEConv.
// Key transforms vs reference:
//  - mean division folded after matmul: (msum/cnt)@W == (msum@W)/cnt
//  - layer-2 Wl2 pre-multiplied into h_var before scatter (linearity of segment_sum),
//    fused into the layer-1 var kernel -> h_var never stored to global.
//  - to_dense_batch is an identity reshape (batch = arange(NC)//K).

template<int LOGQ>
__global__ void scatter_kernel(const float* __restrict__ x, const int* __restrict__ src,
                               const int* __restrict__ dst, float* __restrict__ msum,
                               float* __restrict__ cnt, int E) {
    const int Q = 1 << LOGQ;  // float4s per row
    long gid = (long)blockIdx.x * blockDim.x + threadIdx.x;
    int e = (int)(gid >> LOGQ);
    int q = (int)(gid & (Q - 1));
    if (e >= E) return;
    int s = src[e], d = dst[e];
    float4 v = reinterpret_cast<const float4*>(x)[(size_t)s * Q + q];
    float* o = msum + ((size_t)d * Q + q) * 4;
    atomicAdd(o + 0, v.x);
    atomicAdd(o + 1, v.y);
    atomicAdd(o + 2, v.z);
    atomicAdd(o + 3, v.w);
    if (cnt != nullptr && q == 0) atomicAdd(cnt + d, 1.0f);
}

// h_config = relu(mean1 @ Wl1 + bl1 + x_config @ Wr1)   [NC x 128]
__global__ __launch_bounds__(128) void l1_config_kernel(
    const float* __restrict__ msum, const float* __restrict__ cnt,
    const float* __restrict__ xc, const float* __restrict__ Wl,
    const float* __restrict__ bl, const float* __restrict__ Wr,
    float* __restrict__ h, int nc, int npb) {
    int t = threadIdx.x;
    float wl[64], wr[16];
#pragma unroll
    for (int k = 0; k < 64; ++k) wl[k] = Wl[k * 128 + t];
#pragma unroll
    for (int k = 0; k < 16; ++k) wr[k] = Wr[k * 128 + t];
    float bias = bl[t];
    __shared__ float fs[80];
    int i0 = blockIdx.x * npb;
    int i1 = min(i0 + npb, nc);
    for (int i = i0; i < i1; ++i) {
        float inv = 1.0f / fmaxf(cnt[i], 1.0f);
        if (t < 64) fs[t] = msum[(size_t)i * 64 + t] * inv;
        else if (t < 80) fs[t] = xc[(size_t)i * 16 + (t - 64)];
        __syncthreads();
        float acc = bias;
#pragma unroll
        for (int k = 0; k < 64; ++k) acc += fs[k] * wl[k];
#pragma unroll
        for (int k = 0; k < 16; ++k) acc += fs[64 + k] * wr[k];
        h[(size_t)i * 128 + t] = fmaxf(acc, 0.0f);
        __syncthreads();
    }
}

// hv2 = relu(mean_v @ Wl1' + bl1' + x_var @ Wr1') @ Wl2   [NV x 64]
__global__ __launch_bounds__(128) void l1_var_kernel(
    const float* __restrict__ msum, const float* __restrict__ cnt,
    const float* __restrict__ xv, const float* __restrict__ Wl,
    const float* __restrict__ bl, const float* __restrict__ Wr,
    const float* __restrict__ Wl2, float* __restrict__ hv2,
    int nv, int npb) {
    int t = threadIdx.x;
    int col = t & 63, khalf = t >> 6;
    float wl[16], wr[64], w2[64];
#pragma unroll
    for (int k = 0; k < 16; ++k) wl[k] = Wl[k * 128 + t];
#pragma unroll
    for (int k = 0; k < 64; ++k) wr[k] = Wr[k * 128 + t];
#pragma unroll
    for (int k = 0; k < 64; ++k) w2[k] = Wl2[(size_t)(khalf * 64 + k) * 64 + col];
    float bias = bl[t];
    __shared__ float fs[80];
    __shared__ float hs[128];
    __shared__ float part[128];
    int i0 = blockIdx.x * npb;
    int i1 = min(i0 + npb, nv);
    for (int i = i0; i < i1; ++i) {
        float inv = 1.0f / fmaxf(cnt[i], 1.0f);
        if (t < 16) fs[t] = msum[(size_t)i * 16 + t] * inv;
        else if (t < 80) fs[t] = xv[(size_t)i * 64 + (t - 16)];
        __syncthreads();
        float acc = bias;
#pragma unroll
        for (int k = 0; k < 16; ++k) acc += fs[k] * wl[k];
#pragma unroll
        for (int k = 0; k < 64; ++k) acc += fs[16 + k] * wr[k];
        hs[t] = fmaxf(acc, 0.0f);
        __syncthreads();
        float a2 = 0.0f;
#pragma unroll
        for (int k = 0; k < 64; ++k) a2 += hs[khalf * 64 + k] * w2[k];
        part[t] = a2;
        __syncthreads();
        if (t < 64) hv2[(size_t)i * 64 + t] = part[t] + part[t + 64];
        __syncthreads();
    }
}

// out = msum2/cnt + bl2 + h_config @ Wr2   [NC x 64]
__global__ __launch_bounds__(128) void l2_kernel(
    const float* __restrict__ msum2, const float* __restrict__ cnt,
    const float* __restrict__ h, const float* __restrict__ Wr2,
    const float* __restrict__ bl2, float* __restrict__ out,
    int nc, int npb) {
    int t = threadIdx.x;
    int col = t & 63, khalf = t >> 6;
    float w[64];
#pragma unroll
    for (int k = 0; k < 64; ++k) w[k] = Wr2[(size_t)(khalf * 64 + k) * 64 + col];
    __shared__ float hs[128];
    __shared__ float part[128];
    int i0 = blockIdx.x * npb;
    int i1 = min(i0 + npb, nc);
    for (int i = i0; i < i1; ++i) {
        hs[t] = h[(size_t)i * 128 + t];
        __syncthreads();
        float a = 0.0f;
#pragma unroll
        for (int k = 0; k < 64; ++k) a += hs[khalf * 64 + k] * w[k];
        part[t] = a;
        __syncthreads();
        if (t < 64) {
            float inv = 1.0f / fmaxf(cnt[i], 1.0f);
            out[(size_t)i * 64 + t] =
                part[t] + part[t + 64] + msum2[(size_t)i * 64 + t] * inv + bl2[t];
        }
        __syncthreads();
    }
}

extern "C" void kernel_launch(void* const* d_in, const int* in_sizes, int n_in,
                              void* d_out, int out_size, void* d_ws, size_t ws_size,
                              hipStream_t stream) {
    const float* x_var    = (const float*)d_in[0];
    const float* x_config = (const float*)d_in[1];
    const int* src_v2c = (const int*)d_in[2];
    const int* dst_v2c = (const int*)d_in[3];
    const int* src_c2v = (const int*)d_in[4];
    const int* dst_c2v = (const int*)d_in[5];
    // d_in[6] batch_config: arange(NC)//K -> dense batch is identity reshape
    const float* Wl1_v2c = (const float*)d_in[7];
    const float* bl1_v2c = (const float*)d_in[8];
    const float* Wr1_v2c = (const float*)d_in[9];
    const float* Wl1_c2v = (const float*)d_in[10];
    const float* bl1_c2v = (const float*)d_in[11];
    const float* Wr1_c2v = (const float*)d_in[12];
    const float* Wl2 = (const float*)d_in[13];
    const float* bl2 = (const float*)d_in[14];
    const float* Wr2 = (const float*)d_in[15];
    float* out = (float*)d_out;

    int NV = in_sizes[0] / 64;
    int NC = in_sizes[1] / 16;
    int E  = in_sizes[2];

    float* p = (float*)d_ws;
    float* msum1 = p; p += (size_t)NC * 64;
    float* msumv = p; p += (size_t)NV * 16;
    float* msum2 = p; p += (size_t)NC * 64;
    float* cnt1  = p; p += NC;
    float* cntv  = p; p += NV;
    size_t zero_bytes = (size_t)((char*)p - (char*)d_ws);
    float* hcfg  = p; p += (size_t)NC * 128;

    float* hv2   = p; p += (size_t)NV * 64;

    hipMemsetAsync(d_ws, 0, zero_bytes, stream);

    {   // scatter x_var over v2c edges (64 dims): msum1, cnt1
        long threads = (long)E * 16;
        int blocks = (int)((threads + 255) / 256);
        scatter_kernel<4><<<blocks, 256, 0, stream>>>(x_var, src_v2c, dst_v2c, msum1, cnt1, E);
    }
    {   // scatter x_config over c2v edges (16 dims): msumv, cntv
        long threads = (long)E * 4;
        int blocks = (int)((threads + 255) / 256);
        scatter_kernel<2><<<blocks, 256, 0, stream>>>(x_config, src_c2v, dst_c2v, msumv, cntv, E);
    }

    int npb = 16;
    l1_config_kernel<<<(NC + npb - 1) / npb, 128, 0, stream>>>(
        msum1, cnt1, x_config, Wl1_v2c, bl1_v2c, Wr1_v2c, hcfg, NC, npb);
    l1_var_kernel<<<(NV + npb - 1) / npb, 128, 0, stream>>>(
        msumv, cntv, x_var, Wl1_c2v, bl1_c2v, Wr1_c2v, Wl2, hv2, NV, npb);

    {   // scatter hv2 over v2c edges (64 dims): msum2 (counts already in cnt1)
        long threads = (long)E * 16;
        int blocks = (int)((threads + 255) / 256);
        scatter_kernel<4><<<blocks, 256, 0, stream>>>(hv2, src_v2c, dst_v2c, msum2, nullptr, E);
    }

    l2_kernel<<<(NC + npb - 1) / npb, 128, 0, stream>>>(
        msum2, cnt1, hcfg, Wr2, bl2, out, NC, npb);
}

// Round 2
// 665.122 us; speedup vs baseline: 2.8237x; 2.8237x over previous
//
#include <hip/hip_runtime.h>

// 2-layer hetero SAGEConv, scatter-free.
//  - atomic fp32 scatter-mean replaced by on-device CSR build (int atomics only)
//    + gather-mean fused into the matvec kernels.
//  - (msum/cnt)@W == (msum@W)/cnt ; Wl2 pre-applied to h_var before layer-2 gather.
//  - to_dense_batch is an identity reshape (batch = arange(NC)//K).

#define SCAN_TILE 1024

__global__ void count_kernel(const int* __restrict__ dst, int E, int* __restrict__ cnt) {
    int e = blockIdx.x * 256 + threadIdx.x;
    if (e < E) atomicAdd(&cnt[dst[e]], 1);
}

__global__ void reduce_tile_kernel(const int* __restrict__ x, int n, int* __restrict__ part) {
    __shared__ int s[256];
    int base = blockIdx.x * SCAN_TILE;
    int t = threadIdx.x;
    int sum = 0;
    for (int j = t; j < SCAN_TILE; j += 256) {
        int idx = base + j;
        sum += (idx < n) ? x[idx] : 0;
    }
    s[t] = sum; __syncthreads();
    for (int o = 128; o > 0; o >>= 1) {
        if (t < o) s[t] += s[t + o];
        __syncthreads();
    }
    if (t == 0) part[blockIdx.x] = s[0];
}

__global__ void scan_part_kernel(int* __restrict__ part, int np) {
    __shared__ int s[256];
    int t = threadIdx.x;
    int v = (t < np) ? part[t] : 0;
    s[t] = v; __syncthreads();
    for (int o = 1; o < 256; o <<= 1) {
        int add = (t >= o) ? s[t - o] : 0;
        __syncthreads();
        s[t] += add;
        __syncthreads();
    }
    if (t < np) part[t] = s[t] - v;  // exclusive
}

// off[0..n] exclusive prefix of x[0..n-1]; off[n] = total
__global__ void scan_tile_kernel(const int* __restrict__ x, int n,
                                 const int* __restrict__ part, int* __restrict__ off) {
    __shared__ int s[256];
    int base = blockIdx.x * SCAN_TILE;
    int t = threadIdx.x;
    int idx = base + t * 4;
    int a[4];
#pragma unroll
    for (int j = 0; j < 4; ++j) a[j] = (idx + j < n) ? x[idx + j] : 0;
    int tsum = a[0] + a[1] + a[2] + a[3];
    s[t] = tsum; __syncthreads();
    for (int o = 1; o < 256; o <<= 1) {
        int add = (t >= o) ? s[t - o] : 0;
        __syncthreads();
        s[t] += add;
        __syncthreads();
    }
    int run = s[t] - tsum + part[blockIdx.x];
#pragma unroll
    for (int j = 0; j < 4; ++j) {
        if (idx + j <= n) off[idx + j] = run;
        run += a[j];
    }
}

__global__ void fill_kernel(const int* __restrict__ src, const int* __restrict__ dst, int E,
                            const int* __restrict__ off, int* __restrict__ cur,
                            int* __restrict__ ebuf) {
    int e = blockIdx.x * 256 + threadIdx.x;
    if (e < E) {
        int d = dst[e];
        int p = atomicAdd(&cur[d], 1);
        ebuf[off[d] + p] = src[e];
    }
}

// h_config = relu(gathermean(x_var) @ Wl1 + bl1 + x_config @ Wr1)   [NC x 128]
__global__ __launch_bounds__(128) void l1_config_fused(
    const int* __restrict__ off, const int* __restrict__ ebuf,
    const float* __restrict__ xvar, const float* __restrict__ xc,
    const float* __restrict__ Wl, const float* __restrict__ bl,
    const float* __restrict__ Wr, float* __restrict__ h, int nc, int npb) {
    int t = threadIdx.x;
    float wl[64], wr[16];
#pragma unroll
    for (int k = 0; k < 64; ++k) wl[k] = Wl[k * 128 + t];
#pragma unroll
    for (int k = 0; k < 16; ++k) wr[k] = Wr[k * 128 + t];
    float bias = bl[t];
    __shared__ float4 ps[128];
    __shared__ float fs[80];
    float* psf = (float*)ps;
    int q = t & 15, g = t >> 4;  // 8 groups x 16 lanes, one float4/lane
    int i0 = blockIdx.x * npb, i1 = min(i0 + npb, nc);
    for (int i = i0; i < i1; ++i) {
        int e0 = off[i], e1 = off[i + 1];
        float4 acc = {0.f, 0.f, 0.f, 0.f};
        for (int e = e0 + g; e < e1; e += 8) {
            int s = ebuf[e];
            float4 v = reinterpret_cast<const float4*>(xvar)[(size_t)s * 16 + q];
            acc.x += v.x; acc.y += v.y; acc.z += v.z; acc.w += v.w;
        }
        ps[t] = acc;
        __syncthreads();
        if (t < 64) {
            float inv = 1.0f / fmaxf((float)(e1 - e0), 1.0f);
            float m = 0.f;
#pragma unroll
            for (int gg = 0; gg < 8; ++gg) m += psf[gg * 64 + t];
            fs[t] = m * inv;
        } else if (t < 80) {
            fs[t] = xc[(size_t)i * 16 + (t - 64)];
        }
        __syncthreads();
        float a = bias;
#pragma unroll
        for (int k = 0; k < 64; ++k) a += fs[k] * wl[k];
#pragma unroll
        for (int k = 0; k < 16; ++k) a += fs[64 + k] * wr[k];
        h[(size_t)i * 128 + t] = fmaxf(a, 0.0f);
        __syncthreads();
    }
}

// hv2 = relu(gathermean(x_config) @ Wl1' + bl1' + x_var @ Wr1') @ Wl2   [NV x 64]
__global__ __launch_bounds__(128) void l1_var_fused(
    const int* __restrict__ off, const int* __restrict__ ebuf,
    const float* __restrict__ xcfg, const float* __restrict__ xv,
    const float* __restrict__ Wl, const float* __restrict__ bl,
    const float* __restrict__ Wr, const float* __restrict__ Wl2,
    float* __restrict__ hv2, int nv, int npb) {
    int t = threadIdx.x;
    int col = t & 63, khalf = t >> 6;
    float wl[16], wr[64], w2[64];
#pragma unroll
    for (int k = 0; k < 16; ++k) wl[k] = Wl[k * 128 + t];
#pragma unroll
    for (int k = 0; k < 64; ++k) wr[k] = Wr[k * 128 + t];
#pragma unroll
    for (int k = 0; k < 64; ++k) w2[k] = Wl2[(size_t)(khalf * 64 + k) * 64 + col];
    float bias = bl[t];
    __shared__ float4 ps[128];
    __shared__ float fs[80];
    __shared__ float hs[128];
    __shared__ float part[128];
    float* psf = (float*)ps;
    int q = t & 3, g = t >> 2;  // 32 groups x 4 lanes (row = 4 float4s)
    int i0 = blockIdx.x * npb, i1 = min(i0 + npb, nv);
    for (int i = i0; i < i1; ++i) {
        int e0 = off[i], e1 = off[i + 1];
        float4 acc = {0.f, 0.f, 0.f, 0.f};
        for (int e = e0 + g; e < e1; e += 32) {
            int s = ebuf[e];
            float4 v = reinterpret_cast<const float4*>(xcfg)[(size_t)s * 4 + q];
            acc.x += v.x; acc.y += v.y; acc.z += v.z; acc.w += v.w;
        }
        ps[t] = acc;
        __syncthreads();
        if (t < 16) {
            float inv = 1.0f / fmaxf((float)(e1 - e0), 1.0f);
            float m = 0.f;
#pragma unroll
            for (int gg = 0; gg < 32; ++gg) m += psf[gg * 16 + t];
            fs[t] = m * inv;
        } else if (t >= 16 && t < 80) {
            fs[t] = xv[(size_t)i * 64 + (t - 16)];
        }
        __syncthreads();
        float a = bias;
#pragma unroll
        for (int k = 0; k < 16; ++k) a += fs[k] * wl[k];
#pragma unroll
        for (int k = 0; k < 64; ++k) a += fs[16 + k] * wr[k];
        hs[t] = fmaxf(a, 0.0f);
        __syncthreads();
        float a2 = 0.f;
#pragma unroll
        for (int k = 0; k < 64; ++k) a2 += hs[khalf * 64 + k] * w2[k];
        part[t] = a2;
        __syncthreads();
        if (t < 64) hv2[(size_t)i * 64 + t] = part[t] + part[t + 64];
        __syncthreads();
    }
}

// out = gathermean(hv2) + bl2 + h_config @ Wr2   [NC x 64]
__global__ __launch_bounds__(128) void l2_fused(
    const int* __restrict__ off, const int* __restrict__ ebuf,
    const float* __restrict__ hv2, const float* __restrict__ hcfg,
    const float* __restrict__ Wr2, const float* __restrict__ bl2,
    float* __restrict__ out, int nc, int npb) {
    int t = threadIdx.x;
    int col = t & 63, khalf = t >> 6;
    float w[64];
#pragma unroll
    for (int k = 0; k < 64; ++k) w[k] = Wr2[(size_t)(khalf * 64 + k) * 64 + col];
    __shared__ float4 ps[128];
    __shared__ float hs[128];
    __shared__ float part[128];
    float* psf = (float*)ps;
    int q = t & 15, g = t >> 4;
    int i0 = blockIdx.x * npb, i1 = min(i0 + npb, nc);
    for (int i = i0; i < i1; ++i) {
        hs[t] = hcfg[(size_t)i * 128 + t];
        int e0 = off[i], e1 = off[i + 1];
        float4 acc = {0.f, 0.f, 0.f, 0.f};
        for (int e = e0 + g; e < e1; e += 8) {
            int s = ebuf[e];
            float4 v = reinterpret_cast<const float4*>(hv2)[(size_t)s * 16 + q];
            acc.x += v.x; acc.y += v.y; acc.z += v.z; acc.w += v.w;
        }
        ps[t] = acc;
        __syncthreads();
        float a = 0.f;
#pragma unroll
        for (int k = 0; k < 64; ++k) a += hs[khalf * 64 + k] * w[k];
        part[t] = a;
        __syncthreads();
        if (t < 64) {
            float inv = 1.0f / fmaxf((float)(e1 - e0), 1.0f);
            float m = 0.f;
#pragma unroll
            for (int gg = 0; gg < 8; ++gg) m += psf[gg * 64 + t];
            out[(size_t)i * 64 + t] = m * inv + part[t] + part[t + 64] + bl2[t];
        }
        __syncthreads();
    }
}

extern "C" void kernel_launch(void* const* d_in, const int* in_sizes, int n_in,
                              void* d_out, int out_size, void* d_ws, size_t ws_size,
                              hipStream_t stream) {
    const float* x_var    = (const float*)d_in[0];
    const float* x_config = (const float*)d_in[1];
    const int* src_v2c = (const int*)d_in[2];
    const int* dst_v2c = (const int*)d_in[3];
    const int* src_c2v = (const int*)d_in[4];
    const int* dst_c2v = (const int*)d_in[5];
    // d_in[6] batch_config: arange(NC)//K -> identity reshape
    const float* Wl1_v2c = (const float*)d_in[7];
    const float* bl1_v2c = (const float*)d_in[8];
    const float* Wr1_v2c = (const float*)d_in[9];
    const float* Wl1_c2v = (const float*)d_in[10];
    const float* bl1_c2v = (const float*)d_in[11];
    const float* Wr1_c2v = (const float*)d_in[12];
    const float* Wl2 = (const float*)d_in[13];
    const float* bl2 = (const float*)d_in[14];
    const float* Wr2 = (const float*)d_in[15];
    float* out = (float*)d_out;

    int NV = in_sizes[0] / 64;
    int NC = in_sizes[1] / 16;
    int E  = in_sizes[2];

    // workspace layout (floats first for 16B alignment of float4 reads)
    char* p = (char*)d_ws;
    float* hcfg = (float*)p; p += (size_t)NC * 128 * 4;
    float* hv2  = (float*)p; p += (size_t)NV * 64 * 4;
    int* cnt_c = (int*)p; p += (size_t)NC * 4;   // zeroed region start
    int* cnt_v = (int*)p; p += (size_t)NV * 4;
    int* cur_c = (int*)p; p += (size_t)NC * 4;
    int* cur_v = (int*)p; p += (size_t)NV * 4;
    size_t zero_bytes = (size_t)(p - (char*)cnt_c);
    int* off_c  = (int*)p; p += (size_t)(NC + 1) * 4;
    int* off_v  = (int*)p; p += (size_t)(NV + 1) * 4;
    int* part_c = (int*)p; p += 256 * 4;
    int* part_v = (int*)p; p += 256 * 4;
    int* ebuf_c = (int*)p; p += (size_t)E * 4;
    int* ebuf_v = (int*)p; p += (size_t)E * 4;

    hipMemsetAsync(cnt_c, 0, zero_bytes, stream);

    int eb = (E + 255) / 256;
    count_kernel<<<eb, 256, 0, stream>>>(dst_v2c, E, cnt_c);
    count_kernel<<<eb, 256, 0, stream>>>(dst_c2v, E, cnt_v);

    int nb_c = (NC + 1 + SCAN_TILE - 1) / SCAN_TILE;
    int nb_v = (NV + 1 + SCAN_TILE - 1) / SCAN_TILE;
    reduce_tile_kernel<<<nb_c, 256, 0, stream>>>(cnt_c, NC, part_c);
    scan_part_kernel<<<1, 256, 0, stream>>>(part_c, nb_c);
    scan_tile_kernel<<<nb_c, 256, 0, stream>>>(cnt_c, NC, part_c, off_c);
    reduce_tile_kernel<<<nb_v, 256, 0, stream>>>(cnt_v, NV, part_v);
    scan_part_kernel<<<1, 256, 0, stream>>>(part_v, nb_v);
    scan_tile_kernel<<<nb_v, 256, 0, stream>>>(cnt_v, NV, part_v, off_v);

    fill_kernel<<<eb, 256, 0, stream>>>(src_v2c, dst_v2c, E, off_c, cur_c, ebuf_c);
    fill_kernel<<<eb, 256, 0, stream>>>(src_c2v, dst_c2v, E, off_v, cur_v, ebuf_v);

    int npb = 16;
    l1_config_fused<<<(NC + npb - 1) / npb, 128, 0, stream>>>(
        off_c, ebuf_c, x_var, x_config, Wl1_v2c, bl1_v2c, Wr1_v2c, hcfg, NC, npb);
    l1_var_fused<<<(NV + npb - 1) / npb, 128, 0, stream>>>(
        off_v, ebuf_v, x_config, x_var, Wl1_c2v, bl1_c2v, Wr1_c2v, Wl2, hv2, NV, npb);
    l2_fused<<<(NC + npb - 1) / npb, 128, 0, stream>>>(
        off_c, ebuf_c, hv2, hcfg, Wr2, bl2, out, NC, npb);
}

// Round 3
// 468.154 us; speedup vs baseline: 4.0117x; 1.4207x over previous
//
#include <hip/hip_runtime.h>

// 2-layer hetero SAGEConv, restructured:
//   CSR build (int atomics) -> wave-per-node gather-mean -> dense tile GEMMs.
//  - (msum/cnt)@W == (msum@W)/cnt
//  - Wl2 fused as an in-tile second GEMM stage in the var-layer kernel
//    (h_var[NVx128] never stored; layer-2 gather stays 64-dim).
//  - to_dense_batch is an identity reshape (batch = arange(NC)//K).

#define SCAN_TILE 1024

// ---------------- CSR build ----------------
__global__ void count2_kernel(const int* __restrict__ dst1, const int* __restrict__ dst2,
                              int E, int* __restrict__ c1, int* __restrict__ c2) {
    int g = blockIdx.x * 256 + threadIdx.x;
    if (g < E) atomicAdd(&c1[dst1[g]], 1);
    else if (g < 2 * E) atomicAdd(&c2[dst2[g - E]], 1);
}

__global__ void reduce2_kernel(const int* __restrict__ xc, int nc, int* __restrict__ pc, int nbc,
                               const int* __restrict__ xv, int nv, int* __restrict__ pv) {
    const int* x; int n; int* part; int b;
    if (blockIdx.x < nbc) { x = xc; n = nc; part = pc; b = blockIdx.x; }
    else { x = xv; n = nv; part = pv; b = blockIdx.x - nbc; }
    __shared__ int s[256];
    int base = b * SCAN_TILE, t = threadIdx.x, sum = 0;
    for (int j = t; j < SCAN_TILE; j += 256) { int i = base + j; sum += (i < n) ? x[i] : 0; }
    s[t] = sum; __syncthreads();
    for (int o = 128; o > 0; o >>= 1) { if (t < o) s[t] += s[t + o]; __syncthreads(); }
    if (t == 0) part[b] = s[0];
}

__global__ void scanpart2_kernel(int* __restrict__ pc, int npc, int* __restrict__ pv, int npv) {
    int* part = (blockIdx.x == 0) ? pc : pv;
    int np = (blockIdx.x == 0) ? npc : npv;
    __shared__ int s[256];
    int t = threadIdx.x;
    int v = (t < np) ? part[t] : 0;
    s[t] = v; __syncthreads();
    for (int o = 1; o < 256; o <<= 1) {
        int add = (t >= o) ? s[t - o] : 0; __syncthreads();
        s[t] += add; __syncthreads();
    }
    if (t < np) part[t] = s[t] - v;
}

__global__ void scantile2_kernel(const int* __restrict__ xc, int nc, const int* __restrict__ pc,
                                 int* __restrict__ oc, int nbc,
                                 const int* __restrict__ xv, int nv, const int* __restrict__ pv,
                                 int* __restrict__ ov) {
    const int* x; int n; const int* part; int* off; int b;
    if (blockIdx.x < nbc) { x = xc; n = nc; part = pc; off = oc; b = blockIdx.x; }
    else { x = xv; n = nv; part = pv; off = ov; b = blockIdx.x - nbc; }
    __shared__ int s[256];
    int base = b * SCAN_TILE, t = threadIdx.x;
    int idx = base + t * 4;
    int a[4];
#pragma unroll
    for (int j = 0; j < 4; ++j) a[j] = (idx + j < n) ? x[idx + j] : 0;
    int tsum = a[0] + a[1] + a[2] + a[3];
    s[t] = tsum; __syncthreads();
    for (int o = 1; o < 256; o <<= 1) {
        int add = (t >= o) ? s[t - o] : 0; __syncthreads();
        s[t] += add; __syncthreads();
    }
    int run = s[t] - tsum + part[b];
#pragma unroll
    for (int j = 0; j < 4; ++j) {
        if (idx + j <= n) off[idx + j] = run;
        run += a[j];
    }
}

__global__ void fill2_kernel(const int* __restrict__ s1, const int* __restrict__ d1,
                             const int* __restrict__ s2, const int* __restrict__ d2, int E,
                             const int* __restrict__ o1, int* __restrict__ u1, int* __restrict__ e1,
                             const int* __restrict__ o2, int* __restrict__ u2, int* __restrict__ e2) {
    int g = blockIdx.x * 256 + threadIdx.x;
    if (g < E) {
        int d = d1[g];
        int p = atomicAdd(&u1[d], 1);
        e1[o1[d] + p] = s1[g];
    } else if (g < 2 * E) {
        g -= E;
        int d = d2[g];
        int p = atomicAdd(&u2[d], 1);
        e2[o2[d] + p] = s2[g];
    }
}

// ---------------- gather-mean (wave per node, no barriers) ----------------
__global__ __launch_bounds__(256) void gather_mean64_kernel(
    const int* __restrict__ off, const int* __restrict__ ebuf,
    const float* __restrict__ X, float* __restrict__ M, int n) {
    int lane = threadIdx.x & 63, wid = threadIdx.x >> 6;
    int nw = gridDim.x * 4;
    for (int i = blockIdx.x * 4 + wid; i < n; i += nw) {
        int e0 = off[i], e1 = off[i + 1];
        int deg = e1 - e0;
        float acc = 0.f;
        for (int j0 = 0; j0 < deg; j0 += 64) {
            int m = min(deg - j0, 64);
            int idx = 0;
            if (lane < m) idx = ebuf[e0 + j0 + lane];
            int j = 0;
            for (; j + 4 <= m; j += 4) {
                int s0 = __shfl(idx, j);
                int s1 = __shfl(idx, j + 1);
                int s2 = __shfl(idx, j + 2);
                int s3 = __shfl(idx, j + 3);
                acc += X[(size_t)s0 * 64 + lane];
                acc += X[(size_t)s1 * 64 + lane];
                acc += X[(size_t)s2 * 64 + lane];
                acc += X[(size_t)s3 * 64 + lane];
            }
            for (; j < m; ++j) {
                int s = __shfl(idx, j);
                acc += X[(size_t)s * 64 + lane];
            }
        }
        M[(size_t)i * 64 + lane] = acc / fmaxf((float)deg, 1.0f);
    }
}

__global__ __launch_bounds__(256) void gather_mean16_kernel(
    const int* __restrict__ off, const int* __restrict__ ebuf,
    const float* __restrict__ X, float* __restrict__ M, int n) {
    int lane = threadIdx.x & 63, wid = threadIdx.x >> 6;
    int dlane = lane & 15, eg = lane >> 4;
    int nw = gridDim.x * 4;
    for (int i = blockIdx.x * 4 + wid; i < n; i += nw) {
        int e0 = off[i], e1 = off[i + 1];
        int deg = e1 - e0;
        float acc = 0.f;
        for (int j0 = 0; j0 < deg; j0 += 64) {
            int m = min(deg - j0, 64);
            int idx = 0;
            if (lane < m) idx = ebuf[e0 + j0 + lane];
            for (int j = eg; j < m; j += 4) {
                int s = __shfl(idx, j);
                acc += X[(size_t)s * 16 + dlane];
            }
        }
        acc += __shfl_xor(acc, 16);
        acc += __shfl_xor(acc, 32);
        if (lane < 16) M[(size_t)i * 16 + lane] = acc / fmaxf((float)deg, 1.0f);
    }
}

// ---------------- tile GEMMs ----------------
// F layout in LDS: [k][node] with row stride 68 floats (16B-aligned, low conflict)
template<int D, int ROW0>
__device__ inline void stageF(const float* __restrict__ A, float* __restrict__ Fb,
                              int i0, int n, int t) {
    const int Q = D / 4;          // float4 per row
    const int NPP = 256 / Q;      // nodes per pass
#pragma unroll
    for (int p = 0; p < 64 / NPP; ++p) {
        int nn = t / Q + p * NPP;
        int k4 = t % Q;
        int node = i0 + nn;
        float4 v = make_float4(0.f, 0.f, 0.f, 0.f);
        if (node < n) v = ((const float4*)A)[(size_t)node * Q + k4];
        Fb[(ROW0 + 4 * k4 + 0) * 68 + nn] = v.x;
        Fb[(ROW0 + 4 * k4 + 1) * 68 + nn] = v.y;
        Fb[(ROW0 + 4 * k4 + 2) * 68 + nn] = v.z;
        Fb[(ROW0 + 4 * k4 + 3) * 68 + nn] = v.w;
    }
}

// H[n][128] = relu(M[n][D1] @ Wl + X[n][D2] @ Wr + b), D1+D2 = 80
template<int D1, int D2>
__global__ __launch_bounds__(256) void gemm80_relu_kernel(
    const float* __restrict__ M, const float* __restrict__ X,
    const float* __restrict__ Wl, const float* __restrict__ Wr,
    const float* __restrict__ bias, float* __restrict__ H, int n) {
    __shared__ float Fb[80 * 68];
    __shared__ float Wb[80 * 128];
    int t = threadIdx.x;
    int i0 = blockIdx.x * 64;
    {
        const float4* wl4 = (const float4*)Wl;
        const float4* wr4 = (const float4*)Wr;
        float4* wb4 = (float4*)Wb;
        for (int j = t; j < D1 * 32; j += 256) wb4[j] = wl4[j];
        for (int j = t; j < D2 * 32; j += 256) wb4[D1 * 32 + j] = wr4[j];
    }
    stageF<D1, 0>(M, Fb, i0, n, t);
    stageF<D2, D1>(X, Fb, i0, n, t);
    __syncthreads();
    int tc = t & 15, tn = t >> 4;
    int c0 = tc * 4, n0 = tn * 4;
    float acc[4][8];
#pragma unroll
    for (int j = 0; j < 4; ++j)
#pragma unroll
        for (int jj = 0; jj < 8; ++jj) acc[j][jj] = 0.f;
#pragma unroll 4
    for (int k = 0; k < 80; ++k) {
        float4 f  = *(const float4*)&Fb[k * 68 + n0];
        float4 wa = *(const float4*)&Wb[k * 128 + c0];
        float4 wc = *(const float4*)&Wb[k * 128 + 64 + c0];
        float ff[4] = {f.x, f.y, f.z, f.w};
        float va[4] = {wa.x, wa.y, wa.z, wa.w};
        float vb[4] = {wc.x, wc.y, wc.z, wc.w};
#pragma unroll
        for (int j = 0; j < 4; ++j)
#pragma unroll
            for (int jj = 0; jj < 4; ++jj) {
                acc[j][jj]     += ff[j] * va[jj];
                acc[j][4 + jj] += ff[j] * vb[jj];
            }
    }
    float4 blo = ((const float4*)bias)[tc];
    float4 bhi = ((const float4*)bias)[16 + tc];
#pragma unroll
    for (int j = 0; j < 4; ++j) {
        int node = i0 + n0 + j;
        if (node < n) {
            float4 o1, o2;
            o1.x = fmaxf(acc[j][0] + blo.x, 0.f);
            o1.y = fmaxf(acc[j][1] + blo.y, 0.f);
            o1.z = fmaxf(acc[j][2] + blo.z, 0.f);
            o1.w = fmaxf(acc[j][3] + blo.w, 0.f);
            o2.x = fmaxf(acc[j][4] + bhi.x, 0.f);
            o2.y = fmaxf(acc[j][5] + bhi.y, 0.f);
            o2.z = fmaxf(acc[j][6] + bhi.z, 0.f);
            o2.w = fmaxf(acc[j][7] + bhi.w, 0.f);
            ((float4*)H)[(size_t)node * 32 + tc] = o1;
            ((float4*)H)[(size_t)node * 32 + 16 + tc] = o2;
        }
    }
}

// O[n][64] = relu(M[n][16] @ Wl + X[n][64] @ Wr + b) @ W2
__global__ __launch_bounds__(256) void gemm80_w2_kernel(
    const float* __restrict__ M, const float* __restrict__ X,
    const float* __restrict__ Wl, const float* __restrict__ Wr,
    const float* __restrict__ bias, const float* __restrict__ W2,
    float* __restrict__ O, int n) {
    __shared__ float Fb[128 * 68];   // F[80][68] stage1; Hl[128][68] stage2
    __shared__ float Wb[80 * 128];   // W1 stage1; W2[128][64] stage2
    int t = threadIdx.x;
    int i0 = blockIdx.x * 64;
    {
        const float4* wl4 = (const float4*)Wl;
        const float4* wr4 = (const float4*)Wr;
        float4* wb4 = (float4*)Wb;
        for (int j = t; j < 16 * 32; j += 256) wb4[j] = wl4[j];
        for (int j = t; j < 64 * 32; j += 256) wb4[16 * 32 + j] = wr4[j];
    }
    stageF<16, 0>(M, Fb, i0, n, t);
    stageF<64, 16>(X, Fb, i0, n, t);
    __syncthreads();
    int tc = t & 15, tn = t >> 4;
    int c0 = tc * 4, n0 = tn * 4;
    float acc[4][8];
#pragma unroll
    for (int j = 0; j < 4; ++j)
#pragma unroll
        for (int jj = 0; jj < 8; ++jj) acc[j][jj] = 0.f;
#pragma unroll 4
    for (int k = 0; k < 80; ++k) {
        float4 f  = *(const float4*)&Fb[k * 68 + n0];
        float4 wa = *(const float4*)&Wb[k * 128 + c0];
        float4 wc = *(const float4*)&Wb[k * 128 + 64 + c0];
        float ff[4] = {f.x, f.y, f.z, f.w};
        float va[4] = {wa.x, wa.y, wa.z, wa.w};
        float vb[4] = {wc.x, wc.y, wc.z, wc.w};
#pragma unroll
        for (int j = 0; j < 4; ++j)
#pragma unroll
            for (int jj = 0; jj < 4; ++jj) {
                acc[j][jj]     += ff[j] * va[jj];
                acc[j][4 + jj] += ff[j] * vb[jj];
            }
    }
    __syncthreads();   // everyone done reading Fb/Wb
    {
        float4 blo = ((const float4*)bias)[tc];
        float4 bhi = ((const float4*)bias)[16 + tc];
        float bl[8] = {blo.x, blo.y, blo.z, blo.w, bhi.x, bhi.y, bhi.z, bhi.w};
#pragma unroll
        for (int j = 0; j < 4; ++j)
#pragma unroll
            for (int jj = 0; jj < 4; ++jj) {
                Fb[(c0 + jj) * 68 + n0 + j]      = fmaxf(acc[j][jj] + bl[jj], 0.f);
                Fb[(64 + c0 + jj) * 68 + n0 + j] = fmaxf(acc[j][4 + jj] + bl[4 + jj], 0.f);
            }
        const float4* w24 = (const float4*)W2;
        float4* wb4 = (float4*)Wb;
        for (int j = t; j < 128 * 16; j += 256) wb4[j] = w24[j];
    }
    __syncthreads();
    float a2[4][4];
#pragma unroll
    for (int j = 0; j < 4; ++j)
#pragma unroll
        for (int jj = 0; jj < 4; ++jj) a2[j][jj] = 0.f;
#pragma unroll 4
    for (int k = 0; k < 128; ++k) {
        float4 h = *(const float4*)&Fb[k * 68 + n0];
        float4 w = *(const float4*)&Wb[k * 64 + c0];
        float hh[4] = {h.x, h.y, h.z, h.w};
        float ww[4] = {w.x, w.y, w.z, w.w};
#pragma unroll
        for (int j = 0; j < 4; ++j)
#pragma unroll
            for (int jj = 0; jj < 4; ++jj) a2[j][jj] += hh[j] * ww[jj];
    }
#pragma unroll
    for (int j = 0; j < 4; ++j) {
        int node = i0 + n0 + j;
        if (node < n) {
            float4 o = {a2[j][0], a2[j][1], a2[j][2], a2[j][3]};
            ((float4*)O)[(size_t)node * 16 + tc] = o;
        }
    }
}

// O[n][64] = F[n][128] @ W + Madd[n][64] + b
__global__ __launch_bounds__(256) void gemm128_add_kernel(
    const float* __restrict__ HC, const float* __restrict__ W,
    const float* __restrict__ Madd, const float* __restrict__ bias,
    float* __restrict__ O, int n) {
    __shared__ float Fb[128 * 68];
    __shared__ float Wb[128 * 64];
    int t = threadIdx.x;
    int i0 = blockIdx.x * 64;
    {
        const float4* w4 = (const float4*)W;
        float4* wb4 = (float4*)Wb;
        for (int j = t; j < 128 * 16; j += 256) wb4[j] = w4[j];
    }
    stageF<128, 0>(HC, Fb, i0, n, t);
    __syncthreads();
    int tc = t & 15, tn = t >> 4;
    int c0 = tc * 4, n0 = tn * 4;
    float acc[4][4];
#pragma unroll
    for (int j = 0; j < 4; ++j)
#pragma unroll
        for (int jj = 0; jj < 4; ++jj) acc[j][jj] = 0.f;
#pragma unroll 4
    for (int k = 0; k < 128; ++k) {
        float4 f = *(const float4*)&Fb[k * 68 + n0];
        float4 w = *(const float4*)&Wb[k * 64 + c0];
        float ff[4] = {f.x, f.y, f.z, f.w};
        float ww[4] = {w.x, w.y, w.z, w.w};
#pragma unroll
        for (int j = 0; j < 4; ++j)
#pragma unroll
            for (int jj = 0; jj < 4; ++jj) acc[j][jj] += ff[j] * ww[jj];
    }
    float4 b = ((const float4*)bias)[tc];
#pragma unroll
    for (int j = 0; j < 4; ++j) {
        int node = i0 + n0 + j;
        if (node < n) {
            float4 m = ((const float4*)Madd)[(size_t)node * 16 + tc];
            float4 o;
            o.x = acc[j][0] + m.x + b.x;
            o.y = acc[j][1] + m.y + b.y;
            o.z = acc[j][2] + m.z + b.z;
            o.w = acc[j][3] + m.w + b.w;
            ((float4*)O)[(size_t)node * 16 + tc] = o;
        }
    }
}

extern "C" void kernel_launch(void* const* d_in, const int* in_sizes, int n_in,
                              void* d_out, int out_size, void* d_ws, size_t ws_size,
                              hipStream_t stream) {
    const float* x_var    = (const float*)d_in[0];
    const float* x_config = (const float*)d_in[1];
    const int* src_v2c = (const int*)d_in[2];
    const int* dst_v2c = (const int*)d_in[3];
    const int* src_c2v = (const int*)d_in[4];
    const int* dst_c2v = (const int*)d_in[5];
    const float* Wl1_v2c = (const float*)d_in[7];
    const float* bl1_v2c = (const float*)d_in[8];
    const float* Wr1_v2c = (const float*)d_in[9];
    const float* Wl1_c2v = (const float*)d_in[10];
    const float* bl1_c2v = (const float*)d_in[11];
    const float* Wr1_c2v = (const float*)d_in[12];
    const float* Wl2 = (const float*)d_in[13];
    const float* bl2 = (const float*)d_in[14];
    const float* Wr2 = (const float*)d_in[15];
    float* out = (float*)d_out;

    int NV = in_sizes[0] / 64;
    int NC = in_sizes[1] / 16;
    int E  = in_sizes[2];

    char* p = (char*)d_ws;
    float* Mc  = (float*)p; p += (size_t)NC * 64 * 4;   // also reused as Mc2
    float* Mv  = (float*)p; p += (size_t)NV * 16 * 4;
    float* HC  = (float*)p; p += (size_t)NC * 128 * 4;
    float* hv2 = (float*)p; p += (size_t)NV * 64 * 4;
    int* cnt_c = (int*)p; p += (size_t)NC * 4;          // zeroed region start
    int* cnt_v = (int*)p; p += (size_t)NV * 4;
    int* cur_c = (int*)p; p += (size_t)NC * 4;
    int* cur_v = (int*)p; p += (size_t)NV * 4;
    size_t zero_bytes = (size_t)(p - (char*)cnt_c);
    int* off_c  = (int*)p; p += (size_t)(NC + 1) * 4;
    int* off_v  = (int*)p; p += (size_t)(NV + 1) * 4;
    int* part_c = (int*)p; p += 256 * 4;
    int* part_v = (int*)p; p += 256 * 4;
    int* ebuf_c = (int*)p; p += (size_t)E * 4;
    int* ebuf_v = (int*)p; p += (size_t)E * 4;

    hipMemsetAsync(cnt_c, 0, zero_bytes, stream);

    int eb2 = (2 * E + 255) / 256;
    count2_kernel<<<eb2, 256, 0, stream>>>(dst_v2c, dst_c2v, E, cnt_c, cnt_v);

    int nbc = (NC + 1 + SCAN_TILE - 1) / SCAN_TILE;
    int nbv = (NV + 1 + SCAN_TILE - 1) / SCAN_TILE;
    reduce2_kernel<<<nbc + nbv, 256, 0, stream>>>(cnt_c, NC, part_c, nbc, cnt_v, NV, part_v);
    scanpart2_kernel<<<2, 256, 0, stream>>>(part_c, nbc, part_v, nbv);
    scantile2_kernel<<<nbc + nbv, 256, 0, stream>>>(cnt_c, NC, part_c, off_c, nbc,
                                                    cnt_v, NV, part_v, off_v);
    fill2_kernel<<<eb2, 256, 0, stream>>>(src_v2c, dst_v2c, src_c2v, dst_c2v, E,
                                          off_c, cur_c, ebuf_c, off_v, cur_v, ebuf_v);

    gather_mean64_kernel<<<(NC + 3) / 4, 256, 0, stream>>>(off_c, ebuf_c, x_var, Mc, NC);
    gather_mean16_kernel<<<(NV + 3) / 4, 256, 0, stream>>>(off_v, ebuf_v, x_config, Mv, NV);

    gemm80_relu_kernel<64, 16><<<(NC + 63) / 64, 256, 0, stream>>>(
        Mc, x_config, Wl1_v2c, Wr1_v2c, bl1_v2c, HC, NC);
    gemm80_w2_kernel<<<(NV + 63) / 64, 256, 0, stream>>>(
        Mv, x_var, Wl1_c2v, Wr1_c2v, bl1_c2v, Wl2, hv2, NV);

    // Mc dead after gemm80_relu -> reuse as Mc2
    float* Mc2 = Mc;
    gather_mean64_kernel<<<(NC + 3) / 4, 256, 0, stream>>>(off_c, ebuf_c, hv2, Mc2, NC);

    gemm128_add_kernel<<<(NC + 63) / 64, 256, 0, stream>>>(HC, Wr2, Mc2, bl2, out, NC);
}